// Round 1
// baseline (920.219 us; speedup 1.0000x reference)
//
#include <hip/hip_runtime.h>
#include <hip/hip_bf16.h>
#include <cstddef>

#define FLT_MAX_C 3.402823466e+38f

// ---------------------------------------------------------------------------
// Tiled fp32 GEMM:  C[M,N] = A[M,K] @ Bm[N,K]^T  (+ bias[N] if ADD_BIAS)
// 64x64 tile, BK=16, 256 threads, 4x4 micro-tile per thread.
// ---------------------------------------------------------------------------
template<bool ADD_BIAS>
__global__ __launch_bounds__(256) void gemm_att(
    const float* __restrict__ A, const float* __restrict__ Bm,
    const float* __restrict__ bias, float* __restrict__ C,
    int Mdim, int Ndim, int Kdim)
{
    __shared__ __attribute__((aligned(16))) float As[16][64];
    __shared__ __attribute__((aligned(16))) float Bs[16][64];

    const int tid = threadIdx.x;
    const int m0 = blockIdx.y * 64;
    const int n0 = blockIdx.x * 64;
    const int tx = tid & 15;          // 0..15 -> N micro
    const int ty = tid >> 4;          // 0..15 -> M micro
    const int r  = tid >> 2;          // 0..63 load row
    const int q  = tid & 3;           // 0..3  load col-quad

    float acc[4][4];
#pragma unroll
    for (int i = 0; i < 4; ++i)
#pragma unroll
        for (int j = 0; j < 4; ++j) acc[i][j] = 0.0f;

    for (int k0 = 0; k0 < Kdim; k0 += 16) {
        // --- load A tile (64 rows x 16 k), transposed store As[k][m]
        {
            const int grow = m0 + r;
            const int gcol = k0 + q * 4;
            float4 v = make_float4(0.f, 0.f, 0.f, 0.f);
            if (grow < Mdim) {
                if (gcol + 3 < Kdim) {
                    v = *(const float4*)&A[(size_t)grow * Kdim + gcol];
                } else {
                    float tmp[4] = {0.f, 0.f, 0.f, 0.f};
#pragma unroll
                    for (int e = 0; e < 4; ++e)
                        if (gcol + e < Kdim) tmp[e] = A[(size_t)grow * Kdim + gcol + e];
                    v = make_float4(tmp[0], tmp[1], tmp[2], tmp[3]);
                }
            }
            As[q * 4 + 0][r] = v.x;
            As[q * 4 + 1][r] = v.y;
            As[q * 4 + 2][r] = v.z;
            As[q * 4 + 3][r] = v.w;
        }
        // --- load B tile (64 N-rows x 16 k), transposed store Bs[k][n]
        {
            const int grow = n0 + r;
            const int gcol = k0 + q * 4;
            float4 v = make_float4(0.f, 0.f, 0.f, 0.f);
            if (grow < Ndim) {
                if (gcol + 3 < Kdim) {
                    v = *(const float4*)&Bm[(size_t)grow * Kdim + gcol];
                } else {
                    float tmp[4] = {0.f, 0.f, 0.f, 0.f};
#pragma unroll
                    for (int e = 0; e < 4; ++e)
                        if (gcol + e < Kdim) tmp[e] = Bm[(size_t)grow * Kdim + gcol + e];
                    v = make_float4(tmp[0], tmp[1], tmp[2], tmp[3]);
                }
            }
            Bs[q * 4 + 0][r] = v.x;
            Bs[q * 4 + 1][r] = v.y;
            Bs[q * 4 + 2][r] = v.z;
            Bs[q * 4 + 3][r] = v.w;
        }
        __syncthreads();

#pragma unroll
        for (int kk = 0; kk < 16; ++kk) {
            float4 av = *(const float4*)&As[kk][ty * 4];
            float4 bv = *(const float4*)&Bs[kk][tx * 4];
            float a[4] = {av.x, av.y, av.z, av.w};
            float bb[4] = {bv.x, bv.y, bv.z, bv.w};
#pragma unroll
            for (int i = 0; i < 4; ++i)
#pragma unroll
                for (int j = 0; j < 4; ++j)
                    acc[i][j] = fmaf(a[i], bb[j], acc[i][j]);
        }
        __syncthreads();
    }

#pragma unroll
    for (int i = 0; i < 4; ++i) {
        const int gm = m0 + ty * 4 + i;
        if (gm >= Mdim) continue;
#pragma unroll
        for (int j = 0; j < 4; ++j) {
            const int gn = n0 + tx * 4 + j;
            if (gn >= Ndim) continue;
            float v = acc[i][j];
            if (ADD_BIAS) v += bias[gn];
            C[(size_t)gm * Ndim + gn] = v;
        }
    }
}

// ---------------------------------------------------------------------------
// Per-batch-row masking pipeline. One block (256 threads) per row b.
//   sigma = repeat(z_a,6) + s_b ; minv = min(sigma)
//   pi = (1-phi)*(sigma-minv) ; lam[m] = max_j pi ; wi[m] = argmax_j pi
//   top-50 columns of lam (ties -> lower index)
//   y = tanh(sigma) at (winning column, winner cell) else 0
//   psi_n = max(psi*decay, y) ; phi_n = max(phi*0.5, y) ; x_b_n = psi_n
//   lam2[m] = max_j psi_n
// ---------------------------------------------------------------------------
__global__ __launch_bounds__(256) void rowproc_kernel(
    const float* __restrict__ zA,     // [B,1000]
    const float* __restrict__ sB,     // [B,6000]
    const float* __restrict__ phi,    // [B,6000]
    const float* __restrict__ psi,    // [B,6000]
    const float* __restrict__ decay,  // [6000]
    float* __restrict__ xbn, float* __restrict__ phin, float* __restrict__ psin,
    float* __restrict__ lam2)         // [B,1000]
{
    const int b = blockIdx.x;
    const int tid = threadIdx.x;
    const int lane = tid & 63;
    const int wave = tid >> 6;

    __shared__ float sig[6000];
    __shared__ float lam[1000];
    __shared__ int   wi[1000];
    __shared__ int   cw[1000];
    __shared__ float redf[4];
    __shared__ float rv[4];
    __shared__ int   ri[4];

    const size_t rowTC = (size_t)b * 6000;
    const size_t rowM  = (size_t)b * 1000;

    // --- sigma + row min
    float lmin = FLT_MAX_C;
    for (int t = tid; t < 6000; t += 256) {
        float v = sB[rowTC + t] + zA[rowM + t / 6];
        sig[t] = v;
        lmin = fminf(lmin, v);
    }
#pragma unroll
    for (int off = 32; off > 0; off >>= 1)
        lmin = fminf(lmin, __shfl_down(lmin, off));
    if (lane == 0) redf[wave] = lmin;
    __syncthreads();
    if (tid == 0)
        redf[0] = fminf(fminf(redf[0], redf[1]), fminf(redf[2], redf[3]));
    __syncthreads();
    const float minv = redf[0];

    // --- per-column lam / winner cell; init cw
    for (int m = tid; m < 1000; m += 256) {
        float best = -FLT_MAX_C;
        int bi = 0;
#pragma unroll
        for (int j = 0; j < 6; ++j) {
            const int t = m * 6 + j;
            const float p = (1.0f - phi[rowTC + t]) * (sig[t] - minv);
            if (p > best) { best = p; bi = j; }
        }
        lam[m] = best;
        wi[m] = bi;
        cw[m] = 0;
    }
    __syncthreads();

    // --- iterative top-50 selection (ties -> lower index)
    for (int it = 0; it < 50; ++it) {
        float bv = -FLT_MAX_C;
        int bi = 0x7fffffff;
        for (int m = tid; m < 1000; m += 256) {
            const float v = lam[m];
            if (v > bv || (v == bv && m < bi)) { bv = v; bi = m; }
        }
#pragma unroll
        for (int off = 32; off > 0; off >>= 1) {
            const float ov = __shfl_down(bv, off);
            const int oi = __shfl_down(bi, off);
            if (ov > bv || (ov == bv && oi < bi)) { bv = ov; bi = oi; }
        }
        if (lane == 0) { rv[wave] = bv; ri[wave] = bi; }
        __syncthreads();
        if (tid == 0) {
            float fv = rv[0]; int fi = ri[0];
#pragma unroll
            for (int w = 1; w < 4; ++w)
                if (rv[w] > fv || (rv[w] == fv && ri[w] < fi)) { fv = rv[w]; fi = ri[w]; }
            cw[fi] = 1;
            lam[fi] = -FLT_MAX_C;
        }
        __syncthreads();
    }

    // --- write pass (per column), compute lam2
    for (int m = tid; m < 1000; m += 256) {
        const int won = cw[m];
        const int bj = wi[m];
        float cmax = -FLT_MAX_C;
        const size_t base = rowTC + (size_t)m * 6;
#pragma unroll
        for (int j = 0; j < 6; ++j) {
            const int t = m * 6 + j;
            const float y = (won && j == bj) ? tanhf(sig[t]) : 0.0f;
            const float pv = fmaxf(psi[base + j] * decay[t], y);
            const float fv = fmaxf(phi[base + j] * 0.5f, y);
            psin[base + j] = pv;
            xbn[base + j]  = pv;
            phin[base + j] = fv;
            cmax = fmaxf(cmax, pv);
        }
        lam2[rowM + m] = cmax;
    }
}

// ---------------------------------------------------------------------------
extern "C" void kernel_launch(void* const* d_in, const int* in_sizes, int n_in,
                              void* d_out, int out_size, void* d_ws, size_t ws_size,
                              hipStream_t stream)
{
    const float* x_a   = (const float*)d_in[0];  // [512,2048]
    const float* x_b   = (const float*)d_in[1];  // [512,6000]
    const float* phi   = (const float*)d_in[2];  // [512,6000]
    const float* psi   = (const float*)d_in[3];  // [512,6000]
    const float* W_a   = (const float*)d_in[4];  // [1000,2048]
    const float* W_b   = (const float*)d_in[5];  // [6000,6000]
    const float* W_d   = (const float*)d_in[6];  // [2048,1000]
    const float* b_d   = (const float*)d_in[7];  // [2048]
    const float* decay = (const float*)d_in[8];  // [6000]

    float* out  = (float*)d_out;                       // [512,2048]
    float* xbn  = out + (size_t)512 * 2048;            // [512,6000]
    float* phin = xbn + (size_t)512 * 6000;            // [512,6000]
    float* psin = phin + (size_t)512 * 6000;           // [512,6000]

    float* ws = (float*)d_ws;
    const size_t need = ((size_t)512 * 1000 * 2 + (size_t)512 * 6000) * sizeof(float);

    float* lam2 = ws;                    // [512,1000]  (always in ws: 2 MB)
    float* z_a;                          // [512,1000]
    float* s_b;                          // [512,6000]
    if (ws_size >= need) {
        z_a = ws + 512 * 1000;
        s_b = ws + 2 * 512 * 1000;
    } else {
        // stage in d_out: z_a in out region (consumed before gemm3 writes out);
        // s_b in psin region (rowproc reads its s_b row into LDS before
        // writing its psin row — per-block-private, barrier-ordered).
        z_a = out;
        s_b = psin;
    }

    dim3 blk(256);
    // z_a = x_a @ W_a^T
    gemm_att<false><<<dim3(16, 8), blk, 0, stream>>>(x_a, W_a, nullptr, z_a, 512, 1000, 2048);
    // s_b = x_b @ W_b^T   (dominant: 512x6000x6000)
    gemm_att<false><<<dim3(94, 8), blk, 0, stream>>>(x_b, W_b, nullptr, s_b, 512, 6000, 6000);
    // masking pipeline
    rowproc_kernel<<<512, blk, 0, stream>>>(z_a, s_b, phi, psi, decay, xbn, phin, psin, lam2);
    // out = lam2 @ W_d^T + b_d
    gemm_att<true><<<dim3(32, 8), blk, 0, stream>>>(lam2, W_d, b_d, out, 512, 2048, 1000);
}

// Round 2
// 579.080 us; speedup vs baseline: 1.5891x; 1.5891x over previous
//
#include <hip/hip_runtime.h>
#include <hip/hip_bf16.h>
#include <cstddef>
#include <cstdint>

#define FLT_MAX_C 3.402823466e+38f

typedef __attribute__((ext_vector_type(8))) unsigned short ushort8v;
typedef __attribute__((ext_vector_type(8))) __bf16 bf16x8;
typedef __attribute__((ext_vector_type(16))) float f32x16;

__device__ __forceinline__ unsigned short f2bf_rn(float f) {
    union { float f; unsigned int u; } c; c.f = f;
    return (unsigned short)((c.u + 0x7fffu + ((c.u >> 16) & 1u)) >> 16);
}
__device__ __forceinline__ float bf2f(unsigned short h) {
    union { unsigned int u; float f; } c; c.u = ((unsigned int)h) << 16;
    return c.f;
}

// ---------------------------------------------------------------------------
// Split-bf16 3-pass MFMA GEMM:  C[Ma,Na] = A[Ma,K] @ Bm[Na,K]^T (+bias)
// fp32 in/out; internally A,B split to bf16 hi+lo, acc = hi*hi + hi*lo + lo*hi
// in fp32 AGPRs (rel err ~2^-17, ~= fp32).
// Block tile 64x128, BK=64, 256 threads = 4 waves (2x2), wave tile 32x64
// (two 32x32x16 fragments). Requires Ma % 64 == 0.
// LDS slot-XOR swizzle breaks the row-major 128B-row bank conflict.
// ---------------------------------------------------------------------------
template<bool ADD_BIAS>
__global__ __launch_bounds__(256) void gemm_mfma_split(
    const float* __restrict__ A, const float* __restrict__ Bm,
    const float* __restrict__ bias, float* __restrict__ C,
    int Ma, int Na, int K)
{
    __shared__ unsigned short As_hi[64 * 64];
    __shared__ unsigned short As_lo[64 * 64];
    __shared__ unsigned short Bs_hi[128 * 64];
    __shared__ unsigned short Bs_lo[128 * 64];

    const int tid  = threadIdx.x;
    const int lane = tid & 63;
    const int wid  = tid >> 6;
    const int wm   = wid >> 1;          // wave M half (32 rows)
    const int wn   = wid & 1;           // wave N half (64 cols)
    const int m0   = blockIdx.y * 64;
    const int n0   = blockIdx.x * 128;

    // staging assignment: A row + 16-float seg; B row + 32-float seg
    const int ra = tid & 63;
    const int sa = tid >> 6;            // 0..3
    const int rb = tid >> 1;            // 0..127
    const int sb = tid & 1;             // 0..1

    const float* aptr = A + (size_t)(m0 + ra) * K + sa * 16;
    const int gnb = n0 + rb;
    const float* bptr = (gnb < Na) ? (Bm + (size_t)gnb * K + sb * 32) : nullptr;

    float a_st[16];
    float b_st[32];

    const int nsteps = (K + 63) >> 6;

    auto load_tile = [&](int s) {
        const int k0 = s * 64;
        const int ka = k0 + sa * 16;
        if (ka + 16 <= K) {
#pragma unroll
            for (int q = 0; q < 4; ++q) {
                float4 v = *(const float4*)(aptr + k0 + q * 4);
                a_st[q*4+0] = v.x; a_st[q*4+1] = v.y;
                a_st[q*4+2] = v.z; a_st[q*4+3] = v.w;
            }
        } else {
#pragma unroll
            for (int e = 0; e < 16; ++e)
                a_st[e] = (ka + e < K) ? aptr[k0 + e] : 0.0f;
        }
        const int kb = k0 + sb * 32;
        if (bptr) {
            if (kb + 32 <= K) {
#pragma unroll
                for (int q = 0; q < 8; ++q) {
                    float4 v = *(const float4*)(bptr + k0 + q * 4);
                    b_st[q*4+0] = v.x; b_st[q*4+1] = v.y;
                    b_st[q*4+2] = v.z; b_st[q*4+3] = v.w;
                }
            } else {
#pragma unroll
                for (int e = 0; e < 32; ++e)
                    b_st[e] = (kb + e < K) ? bptr[k0 + e] : 0.0f;
            }
        } else {
#pragma unroll
            for (int e = 0; e < 32; ++e) b_st[e] = 0.0f;
        }
    };

    auto write_tile = [&]() {
#pragma unroll
        for (int w = 0; w < 2; ++w) {
            const int slot = sa * 2 + w;
            const int off  = ra * 64 + ((slot ^ (ra & 7)) << 3);
            ushort8v hv, lv;
#pragma unroll
            for (int e = 0; e < 8; ++e) {
                const float v = a_st[w * 8 + e];
                const unsigned short hb = f2bf_rn(v);
                hv[e] = hb;
                lv[e] = f2bf_rn(v - bf2f(hb));
            }
            *(ushort8v*)&As_hi[off] = hv;
            *(ushort8v*)&As_lo[off] = lv;
        }
#pragma unroll
        for (int w = 0; w < 4; ++w) {
            const int slot = sb * 4 + w;
            const int off  = rb * 64 + ((slot ^ (rb & 7)) << 3);
            ushort8v hv, lv;
#pragma unroll
            for (int e = 0; e < 8; ++e) {
                const float v = b_st[w * 8 + e];
                const unsigned short hb = f2bf_rn(v);
                hv[e] = hb;
                lv[e] = f2bf_rn(v - bf2f(hb));
            }
            *(ushort8v*)&Bs_hi[off] = hv;
            *(ushort8v*)&Bs_lo[off] = lv;
        }
    };

    f32x16 acc0, acc1;
#pragma unroll
    for (int i = 0; i < 16; ++i) { acc0[i] = 0.0f; acc1[i] = 0.0f; }

    const int lr    = lane & 31;
    const int kh    = lane >> 5;        // k-half: 0 -> k0..7, 1 -> k8..15
    const int arow  = wm * 32 + lr;
    const int abase = arow * 64;
    const int axor  = arow & 7;
    const int brow0 = wn * 64 + lr;
    const int brow1 = brow0 + 32;
    const int b0base = brow0 * 64;
    const int b1base = brow1 * 64;
    const int b0xor  = brow0 & 7;
    const int b1xor  = brow1 & 7;

    load_tile(0);

    for (int s = 0; s < nsteps; ++s) {
        if (s) __syncthreads();         // prev tile's LDS reads complete
        write_tile();
        __syncthreads();                // tile visible
        if (s + 1 < nsteps) load_tile(s + 1);   // overlap with MFMA phase

#pragma unroll
        for (int kc = 0; kc < 4; ++kc) {
            const int slot = kc * 2 + kh;
            const int aoff  = abase  + ((slot ^ axor)  << 3);
            const int b0off = b0base + ((slot ^ b0xor) << 3);
            const int b1off = b1base + ((slot ^ b1xor) << 3);
            bf16x8 ah  = __builtin_bit_cast(bf16x8, *(const ushort8v*)&As_hi[aoff]);
            bf16x8 al  = __builtin_bit_cast(bf16x8, *(const ushort8v*)&As_lo[aoff]);
            bf16x8 b0h = __builtin_bit_cast(bf16x8, *(const ushort8v*)&Bs_hi[b0off]);
            bf16x8 b0l = __builtin_bit_cast(bf16x8, *(const ushort8v*)&Bs_lo[b0off]);
            bf16x8 b1h = __builtin_bit_cast(bf16x8, *(const ushort8v*)&Bs_hi[b1off]);
            bf16x8 b1l = __builtin_bit_cast(bf16x8, *(const ushort8v*)&Bs_lo[b1off]);
            acc0 = __builtin_amdgcn_mfma_f32_32x32x16_bf16(ah, b0h, acc0, 0, 0, 0);
            acc1 = __builtin_amdgcn_mfma_f32_32x32x16_bf16(ah, b1h, acc1, 0, 0, 0);
            acc0 = __builtin_amdgcn_mfma_f32_32x32x16_bf16(ah, b0l, acc0, 0, 0, 0);
            acc1 = __builtin_amdgcn_mfma_f32_32x32x16_bf16(ah, b1l, acc1, 0, 0, 0);
            acc0 = __builtin_amdgcn_mfma_f32_32x32x16_bf16(al, b0h, acc0, 0, 0, 0);
            acc1 = __builtin_amdgcn_mfma_f32_32x32x16_bf16(al, b1h, acc1, 0, 0, 0);
        }
    }

    // epilogue: C/D layout col=lane&31, row=(reg&3)+8*(reg>>2)+4*(lane>>5)
    const int col   = lane & 31;
    const int rbase = 4 * kh;
#pragma unroll
    for (int r = 0; r < 16; ++r) {
        const int row = (r & 3) + 8 * (r >> 2) + rbase;
        const int gm  = m0 + wm * 32 + row;      // Ma % 64 == 0 -> always valid
        int gn = n0 + wn * 64 + col;
        if (gn < Na) {
            float v = acc0[r];
            if (ADD_BIAS) v += bias[gn];
            C[(size_t)gm * Na + gn] = v;
        }
        gn += 32;
        if (gn < Na) {
            float v = acc1[r];
            if (ADD_BIAS) v += bias[gn];
            C[(size_t)gm * Na + gn] = v;
        }
    }
}

// ---------------------------------------------------------------------------
// Per-batch-row masking pipeline (unchanged from round 1). One block per row.
// ---------------------------------------------------------------------------
__global__ __launch_bounds__(256) void rowproc_kernel(
    const float* __restrict__ zA,     // [B,1000]
    const float* __restrict__ sB,     // [B,6000]
    const float* __restrict__ phi,    // [B,6000]
    const float* __restrict__ psi,    // [B,6000]
    const float* __restrict__ decay,  // [6000]
    float* __restrict__ xbn, float* __restrict__ phin, float* __restrict__ psin,
    float* __restrict__ lam2)         // [B,1000]
{
    const int b = blockIdx.x;
    const int tid = threadIdx.x;
    const int lane = tid & 63;
    const int wave = tid >> 6;

    __shared__ float sig[6000];
    __shared__ float lam[1000];
    __shared__ int   wi[1000];
    __shared__ int   cw[1000];
    __shared__ float redf[4];
    __shared__ float rv[4];
    __shared__ int   ri[4];

    const size_t rowTC = (size_t)b * 6000;
    const size_t rowM  = (size_t)b * 1000;

    float lmin = FLT_MAX_C;
    for (int t = tid; t < 6000; t += 256) {
        float v = sB[rowTC + t] + zA[rowM + t / 6];
        sig[t] = v;
        lmin = fminf(lmin, v);
    }
#pragma unroll
    for (int off = 32; off > 0; off >>= 1)
        lmin = fminf(lmin, __shfl_down(lmin, off));
    if (lane == 0) redf[wave] = lmin;
    __syncthreads();
    if (tid == 0)
        redf[0] = fminf(fminf(redf[0], redf[1]), fminf(redf[2], redf[3]));
    __syncthreads();
    const float minv = redf[0];

    for (int m = tid; m < 1000; m += 256) {
        float best = -FLT_MAX_C;
        int bi = 0;
#pragma unroll
        for (int j = 0; j < 6; ++j) {
            const int t = m * 6 + j;
            const float p = (1.0f - phi[rowTC + t]) * (sig[t] - minv);
            if (p > best) { best = p; bi = j; }
        }
        lam[m] = best;
        wi[m] = bi;
        cw[m] = 0;
    }
    __syncthreads();

    for (int it = 0; it < 50; ++it) {
        float bv = -FLT_MAX_C;
        int bi = 0x7fffffff;
        for (int m = tid; m < 1000; m += 256) {
            const float v = lam[m];
            if (v > bv || (v == bv && m < bi)) { bv = v; bi = m; }
        }
#pragma unroll
        for (int off = 32; off > 0; off >>= 1) {
            const float ov = __shfl_down(bv, off);
            const int oi = __shfl_down(bi, off);
            if (ov > bv || (ov == bv && oi < bi)) { bv = ov; bi = oi; }
        }
        if (lane == 0) { rv[wave] = bv; ri[wave] = bi; }
        __syncthreads();
        if (tid == 0) {
            float fv = rv[0]; int fi = ri[0];
#pragma unroll
            for (int w = 1; w < 4; ++w)
                if (rv[w] > fv || (rv[w] == fv && ri[w] < fi)) { fv = rv[w]; fi = ri[w]; }
            cw[fi] = 1;
            lam[fi] = -FLT_MAX_C;
        }
        __syncthreads();
    }

    for (int m = tid; m < 1000; m += 256) {
        const int won = cw[m];
        const int bj = wi[m];
        float cmax = -FLT_MAX_C;
        const size_t base = rowTC + (size_t)m * 6;
#pragma unroll
        for (int j = 0; j < 6; ++j) {
            const int t = m * 6 + j;
            const float y = (won && j == bj) ? tanhf(sig[t]) : 0.0f;
            const float pv = fmaxf(psi[base + j] * decay[t], y);
            const float fv = fmaxf(phi[base + j] * 0.5f, y);
            psin[base + j] = pv;
            xbn[base + j]  = pv;
            phin[base + j] = fv;
            cmax = fmaxf(cmax, pv);
        }
        lam2[rowM + m] = cmax;
    }
}

// ---------------------------------------------------------------------------
extern "C" void kernel_launch(void* const* d_in, const int* in_sizes, int n_in,
                              void* d_out, int out_size, void* d_ws, size_t ws_size,
                              hipStream_t stream)
{
    const float* x_a   = (const float*)d_in[0];  // [512,2048]
    const float* x_b   = (const float*)d_in[1];  // [512,6000]
    const float* phi   = (const float*)d_in[2];  // [512,6000]
    const float* psi   = (const float*)d_in[3];  // [512,6000]
    const float* W_a   = (const float*)d_in[4];  // [1000,2048]
    const float* W_b   = (const float*)d_in[5];  // [6000,6000]
    const float* W_d   = (const float*)d_in[6];  // [2048,1000]
    const float* b_d   = (const float*)d_in[7];  // [2048]
    const float* decay = (const float*)d_in[8];  // [6000]

    float* out  = (float*)d_out;                       // [512,2048]
    float* xbn  = out + (size_t)512 * 2048;            // [512,6000]
    float* phin = xbn + (size_t)512 * 6000;            // [512,6000]
    float* psin = phin + (size_t)512 * 6000;           // [512,6000]

    float* ws = (float*)d_ws;
    const size_t need = ((size_t)512 * 1000 * 2 + (size_t)512 * 6000) * sizeof(float);

    float* lam2 = ws;                    // [512,1000]
    float* z_a;                          // [512,1000]
    float* s_b;                          // [512,6000]
    if (ws_size >= need) {
        z_a = ws + 512 * 1000;
        s_b = ws + 2 * 512 * 1000;
    } else {
        z_a = out;       // consumed before final GEMM writes out
        s_b = psin;      // rowproc reads its s_b row into LDS before writing psin
    }

    dim3 blk(256);
    // z_a = x_a @ W_a^T          [512,1000], K=2048
    gemm_mfma_split<false><<<dim3(8, 8), blk, 0, stream>>>(x_a, W_a, nullptr, z_a, 512, 1000, 2048);
    // s_b = x_b @ W_b^T          [512,6000], K=6000 (dominant)
    gemm_mfma_split<false><<<dim3(47, 8), blk, 0, stream>>>(x_b, W_b, nullptr, s_b, 512, 6000, 6000);
    // masking pipeline
    rowproc_kernel<<<512, blk, 0, stream>>>(z_a, s_b, phi, psi, decay, xbn, phin, psin, lam2);
    // out = lam2 @ W_d^T + b_d   [512,2048], K=1000
    gemm_mfma_split<true><<<dim3(16, 8), blk, 0, stream>>>(lam2, W_d, b_d, out, 512, 2048, 1000);
}